// Round 2
// baseline (193.957 us; speedup 1.0000x reference)
//
#include <hip/hip_runtime.h>

#define N_VOX 32768
#define CCH 128
#define EPSV 1e-5f

typedef __attribute__((ext_vector_type(8))) short bfrag;
typedef __attribute__((ext_vector_type(4))) float ffrag;

__device__ __forceinline__ float bf2f(unsigned short u) {
    union { unsigned int i; float f; } c; c.i = ((unsigned int)u) << 16; return c.f;
}
__device__ __forceinline__ unsigned short f2bf(float f) {
    union { float f; unsigned int i; } c; c.f = f;
    unsigned int i = c.i;
    return (unsigned short)((i + 0x7FFFu + ((i >> 16) & 1u)) >> 16);
}

// -------- Kernel 1: LayerNorm, x (C, N) fp32 -> h (N, C) bf16 --------
__global__ __launch_bounds__(256) void ln_kernel(const float* __restrict__ x,
                                                 const float* __restrict__ gamma,
                                                 const float* __restrict__ beta,
                                                 unsigned short* __restrict__ h) {
    __shared__ float xs[128 * 65];
    __shared__ float g[128], b[128];
    __shared__ float ps[256], pq[256];
    __shared__ float muS[64], rsS[64];
    int t = threadIdx.x;
    int v0 = blockIdx.x * 64;
    if (t < 128) { g[t] = gamma[t]; b[t] = beta[t]; }
    int vv = t & 63, cq = t >> 6;
    for (int cb = 0; cb < 32; cb++) {
        int c = cb * 4 + cq;
        xs[c * 65 + vv] = x[(size_t)c * N_VOX + v0 + vv];
    }
    __syncthreads();
    float s = 0.f, sq = 0.f;
    for (int i = 0; i < 32; i++) {
        float val = xs[(cq * 32 + i) * 65 + vv];
        s += val; sq += val * val;
    }
    ps[t] = s; pq[t] = sq;
    __syncthreads();
    if (t < 64) {
        float S = ps[t] + ps[t + 64] + ps[t + 128] + ps[t + 192];
        float Q = pq[t] + pq[t + 64] + pq[t + 128] + pq[t + 192];
        float mu = S * (1.0f / 128.0f);
        float var = Q * (1.0f / 128.0f) - mu * mu;
        muS[t] = mu; rsS[t] = rsqrtf(var + EPSV);
    }
    __syncthreads();
    int c8 = t & 15;
    for (int pass = 0; pass < 4; pass++) {
        int v = pass * 16 + (t >> 4);
        float mu = muS[v], rs = rsS[v];
        union { unsigned short u[8]; uint4 q; } pk;
        #pragma unroll
        for (int i = 0; i < 8; i++) {
            int c = c8 * 8 + i;
            float val = (xs[c * 65 + v] - mu) * rs * g[c] + b[c];
            pk.u[i] = f2bf(val);
        }
        *(uint4*)&h[(size_t)(v0 + v) * 128 + c8 * 8] = pk.q;
    }
}

// -------- Kernel 2: QKV GEMM  qkv[v,o] = h[v,:] . w[o,:] + b[o] --------
// A: h (M=N_VOX, K=128) bf16 row-major; B: w (N=384, K=128) fp32 row-major
__global__ __launch_bounds__(256) void qkv_gemm(const unsigned short* __restrict__ h,
                                                const float* __restrict__ w,
                                                const float* __restrict__ bias,
                                                unsigned short* __restrict__ qkv) {
    __shared__ __align__(16) unsigned short a_s[64 * 136];
    __shared__ __align__(16) unsigned short b_s[64 * 136];
    int t = threadIdx.x;
    int m0 = blockIdx.x * 64, o0 = blockIdx.y * 64;
    {
        int r4 = t >> 4, c8 = t & 15;
        #pragma unroll
        for (int pass = 0; pass < 4; pass++) {
            int r = pass * 16 + r4;
            *(uint4*)&a_s[r * 136 + c8 * 8] =
                *(const uint4*)&h[(size_t)(m0 + r) * 128 + c8 * 8];
            float4 w0 = *(const float4*)&w[(size_t)(o0 + r) * 128 + c8 * 8];
            float4 w1 = *(const float4*)&w[(size_t)(o0 + r) * 128 + c8 * 8 + 4];
            union { unsigned short u[8]; uint4 q; } pk;
            pk.u[0] = f2bf(w0.x); pk.u[1] = f2bf(w0.y);
            pk.u[2] = f2bf(w0.z); pk.u[3] = f2bf(w0.w);
            pk.u[4] = f2bf(w1.x); pk.u[5] = f2bf(w1.y);
            pk.u[6] = f2bf(w1.z); pk.u[7] = f2bf(w1.w);
            *(uint4*)&b_s[r * 136 + c8 * 8] = pk.q;
        }
    }
    __syncthreads();
    int wvi = t >> 6, lane = t & 63, m = lane & 15, quad = lane >> 4;
    ffrag acc[4] = {ffrag{0,0,0,0}, ffrag{0,0,0,0}, ffrag{0,0,0,0}, ffrag{0,0,0,0}};
    #pragma unroll
    for (int kk = 0; kk < 4; kk++) {
        bfrag a = *(bfrag*)&a_s[(wvi * 16 + m) * 136 + kk * 32 + quad * 8];
        #pragma unroll
        for (int nt = 0; nt < 4; nt++) {
            bfrag bb = *(bfrag*)&b_s[(nt * 16 + m) * 136 + kk * 32 + quad * 8];
            acc[nt] = __builtin_amdgcn_mfma_f32_16x16x32_bf16(a, bb, acc[nt], 0, 0, 0);
        }
    }
    #pragma unroll
    for (int nt = 0; nt < 4; nt++) {
        int o = o0 + nt * 16 + m;
        float bs = bias[o];
        int sec = o >> 7;
        int oc = o & 127;
        unsigned short* dst = qkv + (size_t)sec * ((size_t)N_VOX * 128);
        #pragma unroll
        for (int r = 0; r < 4; r++) {
            int vg = m0 + wvi * 16 + quad * 4 + r;
            dst[(size_t)vg * 128 + oc] = f2bf(acc[nt][r] + bs);
        }
    }
}

// -------- Kernel 3: neighborhood attention --------
__global__ __launch_bounds__(256) void attn_kernel(const unsigned short* __restrict__ qb,
                                                   const unsigned short* __restrict__ kb,
                                                   const unsigned short* __restrict__ vb,
                                                   unsigned short* __restrict__ ob) {
    int t = threadIdx.x;
    int wave = t >> 6, lane = t & 63;
    int v = blockIdx.x * 4 + wave;
    int z = v & 31, y = (v >> 5) & 31, x = v >> 10;
    int sx = min(max(x - 1, 0), 29);
    int sy = min(max(y - 1, 0), 29);
    int sz = min(max(z - 1, 0), 29);
    const float scale = 0.17677669529663687f; // 32^-0.5
    #pragma unroll
    for (int hp = 0; hp < 2; hp++) {
        int co = hp * 64 + lane;
        float q = bf2f(qb[(size_t)v * 128 + co]) * scale;
        float s[27], vvv[27];
        #pragma unroll
        for (int j = 0; j < 27; j++) {
            int jx = j / 9, jy = (j % 9) / 3, jz = j % 3;
            int vj = ((sx + jx) << 10) + ((sy + jy) << 5) + (sz + jz);
            size_t idx = (size_t)vj * 128 + co;
            float kkv = bf2f(kb[idx]);
            vvv[j] = bf2f(vb[idx]);
            float p = q * kkv;
            p += __shfl_xor(p, 16);
            p += __shfl_xor(p, 8);
            p += __shfl_xor(p, 4);
            p += __shfl_xor(p, 2);
            p += __shfl_xor(p, 1);
            s[j] = p;
        }
        float mx = s[0];
        #pragma unroll
        for (int j = 1; j < 27; j++) mx = fmaxf(mx, s[j]);
        float sum = 0.f;
        #pragma unroll
        for (int j = 0; j < 27; j++) { s[j] = __expf(s[j] - mx); sum += s[j]; }
        float inv = 1.0f / sum;
        float o = 0.f;
        #pragma unroll
        for (int j = 0; j < 27; j++) o += s[j] * vvv[j];
        ob[(size_t)v * 128 + co] = f2bf(o * inv);
    }
}

// -------- Kernel 4: proj GEMM + bias + residual + transpose to (C, N) --------
__global__ __launch_bounds__(256) void proj_gemm(const unsigned short* __restrict__ a,
                                                 const float* __restrict__ w,
                                                 const float* __restrict__ bias,
                                                 const float* __restrict__ xres,
                                                 float* __restrict__ out) {
    __shared__ __align__(16) unsigned short a_s[64 * 136];
    __shared__ __align__(16) unsigned short b_s[64 * 136];
    int t = threadIdx.x;
    int m0 = blockIdx.x * 64, o0 = blockIdx.y * 64;
    {
        int r4 = t >> 4, c8 = t & 15;
        #pragma unroll
        for (int pass = 0; pass < 4; pass++) {
            int r = pass * 16 + r4;
            *(uint4*)&a_s[r * 136 + c8 * 8] =
                *(const uint4*)&a[(size_t)(m0 + r) * 128 + c8 * 8];
            float4 w0 = *(const float4*)&w[(size_t)(o0 + r) * 128 + c8 * 8];
            float4 w1 = *(const float4*)&w[(size_t)(o0 + r) * 128 + c8 * 8 + 4];
            union { unsigned short u[8]; uint4 q; } pk;
            pk.u[0] = f2bf(w0.x); pk.u[1] = f2bf(w0.y);
            pk.u[2] = f2bf(w0.z); pk.u[3] = f2bf(w0.w);
            pk.u[4] = f2bf(w1.x); pk.u[5] = f2bf(w1.y);
            pk.u[6] = f2bf(w1.z); pk.u[7] = f2bf(w1.w);
            *(uint4*)&b_s[r * 136 + c8 * 8] = pk.q;
        }
    }
    __syncthreads();
    int wvi = t >> 6, lane = t & 63, m = lane & 15, quad = lane >> 4;
    ffrag acc[4] = {ffrag{0,0,0,0}, ffrag{0,0,0,0}, ffrag{0,0,0,0}, ffrag{0,0,0,0}};
    #pragma unroll
    for (int kk = 0; kk < 4; kk++) {
        bfrag av = *(bfrag*)&a_s[(wvi * 16 + m) * 136 + kk * 32 + quad * 8];
        #pragma unroll
        for (int nt = 0; nt < 4; nt++) {
            bfrag bb = *(bfrag*)&b_s[(nt * 16 + m) * 136 + kk * 32 + quad * 8];
            acc[nt] = __builtin_amdgcn_mfma_f32_16x16x32_bf16(av, bb, acc[nt], 0, 0, 0);
        }
    }
    #pragma unroll
    for (int nt = 0; nt < 4; nt++) {
        int o = o0 + nt * 16 + m;
        float bs = bias[o];
        int vg = m0 + wvi * 16 + quad * 4;
        float4 r = *(const float4*)&xres[(size_t)o * N_VOX + vg];
        float4 ov;
        ov.x = acc[nt][0] + bs + r.x;
        ov.y = acc[nt][1] + bs + r.y;
        ov.z = acc[nt][2] + bs + r.z;
        ov.w = acc[nt][3] + bs + r.w;
        *(float4*)&out[(size_t)o * N_VOX + vg] = ov;
    }
}

extern "C" void kernel_launch(void* const* d_in, const int* in_sizes, int n_in,
                              void* d_out, int out_size, void* d_ws, size_t ws_size,
                              hipStream_t stream) {
    const float* x      = (const float*)d_in[0];
    const float* gamma  = (const float*)d_in[1];
    const float* beta   = (const float*)d_in[2];
    const float* qkv_w  = (const float*)d_in[3];
    const float* qkv_b  = (const float*)d_in[4];
    const float* proj_w = (const float*)d_in[5];
    const float* proj_b = (const float*)d_in[6];
    float* out = (float*)d_out;

    unsigned short* h    = (unsigned short*)d_ws;                           // 8 MB
    unsigned short* qkv  = (unsigned short*)((char*)d_ws + (8u << 20));     // 24 MB
    unsigned short* attn = h;                                               // reuse h

    hipLaunchKernelGGL(ln_kernel, dim3(512), dim3(256), 0, stream, x, gamma, beta, h);
    hipLaunchKernelGGL(qkv_gemm, dim3(512, 6), dim3(256), 0, stream, h, qkv_w, qkv_b, qkv);
    const unsigned short* qb = qkv;
    const unsigned short* kb = qkv + (size_t)N_VOX * 128;
    const unsigned short* vb = qkv + (size_t)2 * N_VOX * 128;
    hipLaunchKernelGGL(attn_kernel, dim3(8192), dim3(256), 0, stream, qb, kb, vb, attn);
    hipLaunchKernelGGL(proj_gemm, dim3(512, 2), dim3(256), 0, stream, attn, proj_w, proj_b, x, out);
}

// Round 3
// 138.975 us; speedup vs baseline: 1.3956x; 1.3956x over previous
//
#include <hip/hip_runtime.h>

#define N_VOX 32768
#define CCH 128
#define EPSV 1e-5f

typedef __attribute__((ext_vector_type(8))) short bfrag;
typedef __attribute__((ext_vector_type(4))) float ffrag;

__device__ __forceinline__ float bf2f(unsigned short u) {
    union { unsigned int i; float f; } c; c.i = ((unsigned int)u) << 16; return c.f;
}
__device__ __forceinline__ float bf2f_lo(unsigned int u) {
    union { unsigned int i; float f; } c; c.i = u << 16; return c.f;
}
__device__ __forceinline__ float bf2f_hi(unsigned int u) {
    union { unsigned int i; float f; } c; c.i = u & 0xFFFF0000u; return c.f;
}
__device__ __forceinline__ unsigned short f2bf(float f) {
    union { float f; unsigned int i; } c; c.f = f;
    unsigned int i = c.i;
    return (unsigned short)((i + 0x7FFFu + ((i >> 16) & 1u)) >> 16);
}

// -------- Kernel 1: LayerNorm, x (C, N) fp32 -> h (N, C) bf16 --------
__global__ __launch_bounds__(256) void ln_kernel(const float* __restrict__ x,
                                                 const float* __restrict__ gamma,
                                                 const float* __restrict__ beta,
                                                 unsigned short* __restrict__ h) {
    __shared__ float xs[128 * 65];
    __shared__ float g[128], b[128];
    __shared__ float ps[256], pq[256];
    __shared__ float muS[64], rsS[64];
    int t = threadIdx.x;
    int v0 = blockIdx.x * 64;
    if (t < 128) { g[t] = gamma[t]; b[t] = beta[t]; }
    int vv = t & 63, cq = t >> 6;
    for (int cb = 0; cb < 32; cb++) {
        int c = cb * 4 + cq;
        xs[c * 65 + vv] = x[(size_t)c * N_VOX + v0 + vv];
    }
    __syncthreads();
    float s = 0.f, sq = 0.f;
    for (int i = 0; i < 32; i++) {
        float val = xs[(cq * 32 + i) * 65 + vv];
        s += val; sq += val * val;
    }
    ps[t] = s; pq[t] = sq;
    __syncthreads();
    if (t < 64) {
        float S = ps[t] + ps[t + 64] + ps[t + 128] + ps[t + 192];
        float Q = pq[t] + pq[t + 64] + pq[t + 128] + pq[t + 192];
        float mu = S * (1.0f / 128.0f);
        float var = Q * (1.0f / 128.0f) - mu * mu;
        muS[t] = mu; rsS[t] = rsqrtf(var + EPSV);
    }
    __syncthreads();
    int c8 = t & 15;
    for (int pass = 0; pass < 4; pass++) {
        int v = pass * 16 + (t >> 4);
        float mu = muS[v], rs = rsS[v];
        union { unsigned short u[8]; uint4 q; } pk;
        #pragma unroll
        for (int i = 0; i < 8; i++) {
            int c = c8 * 8 + i;
            float val = (xs[c * 65 + v] - mu) * rs * g[c] + b[c];
            pk.u[i] = f2bf(val);
        }
        *(uint4*)&h[(size_t)(v0 + v) * 128 + c8 * 8] = pk.q;
    }
}

// -------- Kernel 2: QKV GEMM  qkv[v,o] = h[v,:] . w[o,:] + b[o] --------
__global__ __launch_bounds__(256) void qkv_gemm(const unsigned short* __restrict__ h,
                                                const float* __restrict__ w,
                                                const float* __restrict__ bias,
                                                unsigned short* __restrict__ qkv) {
    __shared__ __align__(16) unsigned short a_s[64 * 136];
    __shared__ __align__(16) unsigned short b_s[64 * 136];
    int t = threadIdx.x;
    int m0 = blockIdx.x * 64, o0 = blockIdx.y * 64;
    {
        int r4 = t >> 4, c8 = t & 15;
        #pragma unroll
        for (int pass = 0; pass < 4; pass++) {
            int r = pass * 16 + r4;
            *(uint4*)&a_s[r * 136 + c8 * 8] =
                *(const uint4*)&h[(size_t)(m0 + r) * 128 + c8 * 8];
            float4 w0 = *(const float4*)&w[(size_t)(o0 + r) * 128 + c8 * 8];
            float4 w1 = *(const float4*)&w[(size_t)(o0 + r) * 128 + c8 * 8 + 4];
            union { unsigned short u[8]; uint4 q; } pk;
            pk.u[0] = f2bf(w0.x); pk.u[1] = f2bf(w0.y);
            pk.u[2] = f2bf(w0.z); pk.u[3] = f2bf(w0.w);
            pk.u[4] = f2bf(w1.x); pk.u[5] = f2bf(w1.y);
            pk.u[6] = f2bf(w1.z); pk.u[7] = f2bf(w1.w);
            *(uint4*)&b_s[r * 136 + c8 * 8] = pk.q;
        }
    }
    __syncthreads();
    int wvi = t >> 6, lane = t & 63, m = lane & 15, quad = lane >> 4;
    ffrag acc[4] = {ffrag{0,0,0,0}, ffrag{0,0,0,0}, ffrag{0,0,0,0}, ffrag{0,0,0,0}};
    #pragma unroll
    for (int kk = 0; kk < 4; kk++) {
        bfrag a = *(bfrag*)&a_s[(wvi * 16 + m) * 136 + kk * 32 + quad * 8];
        #pragma unroll
        for (int nt = 0; nt < 4; nt++) {
            bfrag bb = *(bfrag*)&b_s[(nt * 16 + m) * 136 + kk * 32 + quad * 8];
            acc[nt] = __builtin_amdgcn_mfma_f32_16x16x32_bf16(a, bb, acc[nt], 0, 0, 0);
        }
    }
    #pragma unroll
    for (int nt = 0; nt < 4; nt++) {
        int o = o0 + nt * 16 + m;
        float bs = bias[o];
        int sec = o >> 7;
        int oc = o & 127;
        unsigned short* dst = qkv + (size_t)sec * ((size_t)N_VOX * 128);
        #pragma unroll
        for (int r = 0; r < 4; r++) {
            int vg = m0 + wvi * 16 + quad * 4 + r;
            dst[(size_t)vg * 128 + oc] = f2bf(acc[nt][r] + bs);
        }
    }
}

// -------- Kernel 3: neighborhood attention (packed 2 channels/lane) --------
// Lane l owns channels {2l, 2l+1}; head = l>>4; reduction group = 16 lanes.
__global__ __launch_bounds__(256) void attn_kernel(const unsigned int* __restrict__ qb,
                                                   const unsigned int* __restrict__ kb,
                                                   const unsigned int* __restrict__ vb,
                                                   unsigned int* __restrict__ ob) {
    int t = threadIdx.x;
    int wave = t >> 6, lane = t & 63;
    int v = blockIdx.x * 4 + wave;
    int z = v & 31, y = (v >> 5) & 31, x = v >> 10;
    int sx = min(max(x - 1, 0), 29);
    int sy = min(max(y - 1, 0), 29);
    int sz = min(max(z - 1, 0), 29);
    int base = (sx << 10) + (sy << 5) + sz;   // neighbor (0,0,0) voxel index
    const float scale = 0.17677669529663687f; // 32^-0.5
    unsigned int qpk = qb[(size_t)v * 64 + lane];
    float q0 = bf2f_lo(qpk) * scale;
    float q1 = bf2f_hi(qpk) * scale;
    float s[27];
    unsigned int vpk[27];
    #pragma unroll
    for (int j = 0; j < 27; j++) {
        int jx = j / 9, jy = (j % 9) / 3, jz = j % 3;
        int vj = base + (jx << 10) + (jy << 5) + jz;
        size_t idx = (size_t)vj * 64 + lane;
        unsigned int kpk = kb[idx];
        vpk[j] = vb[idx];
        float p = q0 * bf2f_lo(kpk) + q1 * bf2f_hi(kpk);
        p += __shfl_xor(p, 8);
        p += __shfl_xor(p, 4);
        p += __shfl_xor(p, 2);
        p += __shfl_xor(p, 1);
        s[j] = p;
    }
    float mx = s[0];
    #pragma unroll
    for (int j = 1; j < 27; j++) mx = fmaxf(mx, s[j]);
    float sum = 0.f;
    #pragma unroll
    for (int j = 0; j < 27; j++) { s[j] = __expf(s[j] - mx); sum += s[j]; }
    float inv = 1.0f / sum;
    float o0 = 0.f, o1 = 0.f;
    #pragma unroll
    for (int j = 0; j < 27; j++) {
        o0 += s[j] * bf2f_lo(vpk[j]);
        o1 += s[j] * bf2f_hi(vpk[j]);
    }
    unsigned int opk = ((unsigned int)f2bf(o0 * inv)) | (((unsigned int)f2bf(o1 * inv)) << 16);
    ob[(size_t)v * 64 + lane] = opk;
}

// -------- Kernel 4: proj GEMM + bias + residual + transpose to (C, N) --------
__global__ __launch_bounds__(256) void proj_gemm(const unsigned short* __restrict__ a,
                                                 const float* __restrict__ w,
                                                 const float* __restrict__ bias,
                                                 const float* __restrict__ xres,
                                                 float* __restrict__ out) {
    __shared__ __align__(16) unsigned short a_s[64 * 136];
    __shared__ __align__(16) unsigned short b_s[64 * 136];
    int t = threadIdx.x;
    int m0 = blockIdx.x * 64, o0 = blockIdx.y * 64;
    {
        int r4 = t >> 4, c8 = t & 15;
        #pragma unroll
        for (int pass = 0; pass < 4; pass++) {
            int r = pass * 16 + r4;
            *(uint4*)&a_s[r * 136 + c8 * 8] =
                *(const uint4*)&a[(size_t)(m0 + r) * 128 + c8 * 8];
            float4 w0 = *(const float4*)&w[(size_t)(o0 + r) * 128 + c8 * 8];
            float4 w1 = *(const float4*)&w[(size_t)(o0 + r) * 128 + c8 * 8 + 4];
            union { unsigned short u[8]; uint4 q; } pk;
            pk.u[0] = f2bf(w0.x); pk.u[1] = f2bf(w0.y);
            pk.u[2] = f2bf(w0.z); pk.u[3] = f2bf(w0.w);
            pk.u[4] = f2bf(w1.x); pk.u[5] = f2bf(w1.y);
            pk.u[6] = f2bf(w1.z); pk.u[7] = f2bf(w1.w);
            *(uint4*)&b_s[r * 136 + c8 * 8] = pk.q;
        }
    }
    __syncthreads();
    int wvi = t >> 6, lane = t & 63, m = lane & 15, quad = lane >> 4;
    ffrag acc[4] = {ffrag{0,0,0,0}, ffrag{0,0,0,0}, ffrag{0,0,0,0}, ffrag{0,0,0,0}};
    #pragma unroll
    for (int kk = 0; kk < 4; kk++) {
        bfrag av = *(bfrag*)&a_s[(wvi * 16 + m) * 136 + kk * 32 + quad * 8];
        #pragma unroll
        for (int nt = 0; nt < 4; nt++) {
            bfrag bb = *(bfrag*)&b_s[(nt * 16 + m) * 136 + kk * 32 + quad * 8];
            acc[nt] = __builtin_amdgcn_mfma_f32_16x16x32_bf16(av, bb, acc[nt], 0, 0, 0);
        }
    }
    #pragma unroll
    for (int nt = 0; nt < 4; nt++) {
        int o = o0 + nt * 16 + m;
        float bs = bias[o];
        int vg = m0 + wvi * 16 + quad * 4;
        float4 r = *(const float4*)&xres[(size_t)o * N_VOX + vg];
        float4 ov;
        ov.x = acc[nt][0] + bs + r.x;
        ov.y = acc[nt][1] + bs + r.y;
        ov.z = acc[nt][2] + bs + r.z;
        ov.w = acc[nt][3] + bs + r.w;
        *(float4*)&out[(size_t)o * N_VOX + vg] = ov;
    }
}

extern "C" void kernel_launch(void* const* d_in, const int* in_sizes, int n_in,
                              void* d_out, int out_size, void* d_ws, size_t ws_size,
                              hipStream_t stream) {
    const float* x      = (const float*)d_in[0];
    const float* gamma  = (const float*)d_in[1];
    const float* beta   = (const float*)d_in[2];
    const float* qkv_w  = (const float*)d_in[3];
    const float* qkv_b  = (const float*)d_in[4];
    const float* proj_w = (const float*)d_in[5];
    const float* proj_b = (const float*)d_in[6];
    float* out = (float*)d_out;

    unsigned short* h    = (unsigned short*)d_ws;                           // 8 MB
    unsigned short* qkv  = (unsigned short*)((char*)d_ws + (8u << 20));     // 24 MB
    unsigned short* attn = h;                                               // reuse h

    hipLaunchKernelGGL(ln_kernel, dim3(512), dim3(256), 0, stream, x, gamma, beta, h);
    hipLaunchKernelGGL(qkv_gemm, dim3(512, 6), dim3(256), 0, stream, h, qkv_w, qkv_b, qkv);
    const unsigned short* qb = qkv;
    const unsigned short* kb = qkv + (size_t)N_VOX * 128;
    const unsigned short* vb = qkv + (size_t)2 * N_VOX * 128;
    hipLaunchKernelGGL(attn_kernel, dim3(8192), dim3(256), 0, stream,
                       (const unsigned int*)qb, (const unsigned int*)kb,
                       (const unsigned int*)vb, (unsigned int*)attn);
    hipLaunchKernelGGL(proj_gemm, dim3(512, 2), dim3(256), 0, stream, attn, proj_w, proj_b, x, out);
}